// Round 11
// baseline (26.583 us; speedup 1.0000x reference)
//
#include <hip/hip_runtime.h>
#include <stdint.h>

#define BB 512
#define NN 8192
#define KK 16
#define HH 16

typedef _Float16 f16;
typedef _Float16 f16x4 __attribute__((ext_vector_type(4)));
typedef float f32x4 __attribute__((ext_vector_type(4)));

// ---------------------------------------------------------------------------
// Kernel 1: pack signs of x (+-1) into transposed-word bitmask.
// xpT[j*16+w] bit i = (x[(w*32+i)*N+j] > 0).  512 KB, L2/L3-resident.
// 256 blocks x 512 thr: coalesced x reads, LDS-staged contiguous 2KB write.
// ---------------------------------------------------------------------------
__global__ __launch_bounds__(512) void pack_kernel(const float* __restrict__ x,
                                                   uint32_t* __restrict__ xpT) {
    __shared__ uint32_t pstage[32 * 17];
    const int tid = threadIdx.x;
    const int j0  = blockIdx.x * 32;
    const int jl  = tid & 31;   // 32 consecutive j -> 128B coalesced reads
    const int wq  = tid >> 5;   // word group 0..15
    uint32_t word = 0u;
#pragma unroll
    for (int i = 0; i < 32; ++i)
        word |= (x[(size_t)(wq * 32 + i) * NN + j0 + jl] > 0.0f ? 1u : 0u) << i;
    pstage[jl * 17 + wq] = word;
    __syncthreads();
    xpT[(size_t)j0 * 16 + tid] = pstage[(tid >> 4) * 17 + (tid & 15)];
}

// ---------------------------------------------------------------------------
// Kernel 2: grid (1024,2) = 2048 blocks -> 2 generations at 4 blocks/CU.
// Block = 8n x 256b, 512 thr = 8 waves; wave = 1 n (self-contained, no
// prologue barriers).  CHANGE vs R10: the sigmoid epilogue is fully
// deferred — all 16 tiles do {ds_read wk, unpack, MFMA, relu-dot, one f16
// ds_write to zbuf} with NO intervening LDS reads, so there is no
// lgkmcnt(0) drain every 4 tiles and all 16 MFMA chains interleave freely.
// One dense pass at the end: each lane finishes 4 outputs (ds_read_b64 of
// 4 f16 partials + adds + exp + rcp).  Output transpose fused via
// tile[256][12]; single __syncthreads before the store.
// LDS: wbuf 5K + zbuf(f16) 16K + tile 12K = 33K -> 4 blocks/CU, 8 waves/SIMD.
// ---------------------------------------------------------------------------
__global__ __launch_bounds__(512, 8) void mfma_kernel(
    const uint32_t* __restrict__ xpT, const float* __restrict__ W1,
    const int* __restrict__ neighs, const float* __restrict__ b1,
    const float* __restrict__ W2, const float* __restrict__ b2,
    float* __restrict__ out) {
    __shared__ __align__(16) uint32_t wbuf[8][8 * 20];  // [wave][w*20+k]
    __shared__ __align__(8)  f16  zbuf[8][256][4];      // [wave][b_local][lg]
    __shared__ __align__(16) float tile[256 * 12];      // [b_local][n_local]

    const int tid = threadIdx.x;
    const int wv  = tid >> 6;        // 0..7  (= n_local)
    const int l   = tid & 63;
    const int l15 = l & 15;
    const int lg  = l >> 4;          // 0..3
    const int n0  = blockIdx.x * 8;
    const int b0  = blockIdx.y * 256;
    const int w0  = blockIdx.y * 8;  // word base for this b-half

    const int n = n0 + wv;

    // ---- issue all independent global loads up front (no barriers) ----
    const int j = neighs[n * KK + l15];                  // 64B broadcast
    const uint2 g = *(const uint2*)&xpT[(size_t)j * 16 + w0 + lg * 2];
    const float* W1n = W1 + (size_t)n * (KK * HH) + lg * 4 * HH + l15;
    const float a0 = W1n[0 * HH];
    const float a1 = W1n[1 * HH];
    const float a2 = W1n[2 * HH];
    const float a3 = W1n[3 * HH];
    const float4 b1v = *(const float4*)(b1 + (size_t)n * HH + lg * 4);
    const float4 w2v = *(const float4*)(W2 + (size_t)n * HH + lg * 4);
    const float b2n = b2[n];

    const f16x4 a = {(f16)a0, (f16)a1, (f16)a2, (f16)a3};
    const f32x4 cinit = {b1v.x, b1v.y, b1v.z, b1v.w};

    // ---- stage sign words to wave-private LDS (lgkmcnt-ordered) ----
    wbuf[wv][(2 * lg) * 20 + l15]     = g.x;
    wbuf[wv][(2 * lg + 1) * 20 + l15] = g.y;

    // ---- 16 independent tile chains, no LDS reads of freshly-written
    //      data until the single dense pass below ----
#pragma unroll
    for (int tb = 0; tb < 16; ++tb) {
        const int wg = tb >> 1;
        const uint4 wk = *(const uint4*)&wbuf[wv][wg * 20 + lg * 4];
        const int pos = (tb & 1) * 16 + l15;  // bit index within word
        // bit=1 -> +1.0f16 (0x3C00), bit=0 -> -1.0f16 (0xBC00)
        const uint32_t d0 = 0xBC00BC00u ^ (((wk.x >> pos) & 1u) << 15) ^
                            ((wk.y >> pos) << 31);
        const uint32_t d1 = 0xBC00BC00u ^ (((wk.z >> pos) & 1u) << 15) ^
                            ((wk.w >> pos) << 31);
        uint2 bdu; bdu.x = d0; bdu.y = d1;
        const f16x4 bfr = __builtin_bit_cast(f16x4, bdu);

        const f32x4 acc = __builtin_amdgcn_mfma_f32_16x16x16f16(
            a, bfr, cinit, 0, 0, 0);

        // relu-dot partial: zp(lg, b=tb*16+l15)
        const float zp =
            fmaf(fmaxf(acc[0], 0.f), w2v.x,
            fmaf(fmaxf(acc[1], 0.f), w2v.y,
            fmaf(fmaxf(acc[2], 0.f), w2v.z,
                 fmaxf(acc[3], 0.f) * w2v.w)));
        zbuf[wv][tb * 16 + l15][lg] = (f16)zp;
    }

    // ---- single dense pass: 4 outputs per lane ----
#pragma unroll
    for (int p = 0; p < 4; ++p) {
        const int bl = p * 64 + l;
        const f16x4 zv = *(const f16x4*)&zbuf[wv][bl][0];
        const float z = ((float)zv[0] + (float)zv[1]) +
                        ((float)zv[2] + (float)zv[3]) + b2n;
        const float r = __builtin_amdgcn_rcpf(1.0f + __expf(-z));
        tile[bl * 12 + wv] = r;
    }
    __syncthreads();

    // stores: 2 lanes cover one 32B half-row of out[b][n0..n0+7]
    const int row = tid >> 1;
    const int c   = (tid & 1) * 4;
    const float4 v = *(const float4*)&tile[row * 12 + c];
    *(float4*)(out + (size_t)(b0 + row) * NN + n0 + c) = v;
}

// ---------------------------------------------------------------------------
// Fallback scalar kernel (only if workspace is too small).
// ---------------------------------------------------------------------------
__global__ __launch_bounds__(512) void scalar_kernel(
    const float* __restrict__ x, const int* __restrict__ neighs,
    const float* __restrict__ W1, const float* __restrict__ b1,
    const float* __restrict__ W2, const float* __restrict__ b2,
    float* __restrict__ outp) {
    const int n = blockIdx.x;
    const int b = threadIdx.x;
    const int* nb = neighs + n * KK;
    const float* W1n = W1 + (size_t)n * KK * HH;
    const float* b1n = b1 + (size_t)n * HH;
    const float* W2n = W2 + (size_t)n * HH;

    float s[KK];
#pragma unroll
    for (int k = 0; k < KK; ++k) s[k] = x[(size_t)b * NN + nb[k]];

    float acc[HH];
#pragma unroll
    for (int h = 0; h < HH; ++h) acc[h] = b1n[h];
#pragma unroll
    for (int k = 0; k < KK; ++k)
#pragma unroll
        for (int h = 0; h < HH; ++h)
            acc[h] = fmaf(s[k], W1n[k * HH + h], acc[h]);

    float z = b2[n];
#pragma unroll
    for (int h = 0; h < HH; ++h)
        z = fmaf(fmaxf(acc[h], 0.0f), W2n[h], z);
    outp[(size_t)b * NN + n] = 1.0f / (1.0f + __expf(-z));
}

extern "C" void kernel_launch(void* const* d_in, const int* in_sizes, int n_in,
                              void* d_out, int out_size, void* d_ws, size_t ws_size,
                              hipStream_t stream) {
    const float* x      = (const float*)d_in[0];
    const int*   neighs = (const int*)d_in[1];
    const float* W1     = (const float*)d_in[2];
    const float* b1     = (const float*)d_in[3];
    const float* W2     = (const float*)d_in[4];
    const float* b2     = (const float*)d_in[5];
    float* out = (float*)d_out;

    const size_t pack_bytes = (size_t)NN * 16 * sizeof(uint32_t);  // 512 KB

    if (ws_size >= pack_bytes) {
        uint32_t* xpT = (uint32_t*)d_ws;
        pack_kernel<<<NN / 32, 512, 0, stream>>>(x, xpT);
        mfma_kernel<<<dim3(NN / 8, BB / 256), 512, 0, stream>>>(
            xpT, W1, neighs, b1, W2, b2, out);
    } else {
        scalar_kernel<<<NN, BB, 0, stream>>>(x, neighs, W1, b1, W2, b2, out);
    }
}